// Round 5
// baseline (809.198 us; speedup 1.0000x reference)
//
#include <hip/hip_runtime.h>
#include <cmath>

#define N_IMG   8
#define PRE     1000
#define K_SEL   5000
#define NBIN    4096
#define TIE_CAP 4096
#define IMG_F   1344.0f
#define S_NEGINF 0x007FFFFFu
#define MAT_W   160            // fallback path: u32 words per rank-space row

__constant__ int c_W[5]   = {336,168,84,42,21};
__constant__ int c_HW[5]  = {112896,28224,7056,1764,441};
__constant__ int c_OFF[5] = {0,338688,423360,444528,449820};

__device__ __forceinline__ unsigned f2s(float f){
  unsigned u = __float_as_uint(f);
  return (u & 0x80000000u) ? ~u : (u | 0x80000000u);
}
__device__ __forceinline__ float s2f(unsigned s){
  unsigned u = (s & 0x80000000u) ? (s & 0x7FFFFFFFu) : ~s;
  return __uint_as_float(u);
}
__device__ __forceinline__ const float* sel5(int l, const float* p0,const float* p1,const float* p2,const float* p3,const float* p4){
  switch(l){case 0:return p0;case 1:return p1;case 2:return p2;case 3:return p3;default:return p4;}
}

struct BoxV { float x1,y1,x2,y2; bool valid; };

// Bit-faithful torchvision BoxCoder.decode + clip + min-size validity.
__device__ BoxV decode_box(int lvl, int t, int n, const float* dl, const float* anchors){
  int HW = c_HW[lvl], W = c_W[lvl];
  int a = t % 3, pos = t / 3;          // t = (h*W+w)*3 + a
  int h = pos / W, w = pos - h*W;
  int g = c_OFF[lvl] + t;
  const float* an = anchors + (size_t)4*(size_t)g;
  float a0=an[0], a1=an[1], a2=an[2], a3=an[3];
  float aw = __fsub_rn(a2,a0), ah = __fsub_rn(a3,a1);
  float acx = __fadd_rn(a0, __fmul_rn(0.5f,aw));
  float acy = __fadd_rn(a1, __fmul_rn(0.5f,ah));
  const float* dp = dl + ((size_t)n*12 + (size_t)a*4)*(size_t)HW + (size_t)h*W + (size_t)w;
  float dx = dp[0], dy = dp[HW], dwv = dp[2*(size_t)HW], dhv = dp[3*(size_t)HW];
  const float CLAMP = (float)4.135166556742356;  // log(1000/16)
  dwv = fminf(dwv, CLAMP); dhv = fminf(dhv, CLAMP);
  float pcx = __fadd_rn(__fmul_rn(dx,aw), acx);
  float pcy = __fadd_rn(__fmul_rn(dy,ah), acy);
  float pw = __fmul_rn((float)::exp((double)dwv), aw);
  float ph = __fmul_rn((float)::exp((double)dhv), ah);
  float hx = __fmul_rn(0.5f,pw), hy = __fmul_rn(0.5f,ph);
  BoxV b;
  b.x1 = fminf(fmaxf(__fsub_rn(pcx,hx),0.0f),IMG_F);
  b.y1 = fminf(fmaxf(__fsub_rn(pcy,hy),0.0f),IMG_F);
  b.x2 = fminf(fmaxf(__fadd_rn(pcx,hx),0.0f),IMG_F);
  b.y2 = fminf(fmaxf(__fadd_rn(pcy,hy),0.0f),IMG_F);
  b.valid = (__fsub_rn(b.x2,b.x1) >= 1e-3f) && (__fsub_rn(b.y2,b.y1) >= 1e-3f);
  return b;
}

// key = (~s_eff)<<22 | lvl<<19 | t : ascending sort == (score desc, level asc, idx asc)
__device__ unsigned long long make_key(unsigned s, int lvl, int t, int n, const float* dl, const float* anchors){
  BoxV b = decode_box(lvl,t,n,dl,anchors);
  unsigned se = b.valid ? s : S_NEGINF;     // invalid -> skey = -inf
  return ((unsigned long long)(~se) << 22) | ((unsigned long long)(unsigned)lvl << 19) | (unsigned long long)(unsigned)t;
}

// ---------------- K1: per-(image,level) 12-bit score histogram ----------------
__global__ __launch_bounds__(256) void k_hist(const float* o0,const float* o1,const float* o2,const float* o3,const float* o4,
                                              unsigned* hist){
  int grp = blockIdx.y; int n = grp/5, lvl = grp - n*5;
  const float* ob = sel5(lvl,o0,o1,o2,o3,o4);
  int HW = c_HW[lvl], M = 3*HW;
  ob += (size_t)n*(size_t)M;
  __shared__ unsigned lh[NBIN];
  for (int b = threadIdx.x; b < NBIN; b += 256) lh[b] = 0;
  __syncthreads();
  int stride = gridDim.x*256;
  for (int i = blockIdx.x*256 + threadIdx.x; i < M; i += stride){
    unsigned s = f2s(ob[i]);
    atomicAdd(&lh[s >> 20], 1u);
  }
  __syncthreads();
  unsigned* gh = hist + (size_t)grp*NBIN;
  for (int b = threadIdx.x; b < NBIN; b += 256){ unsigned v = lh[b]; if (v) atomicAdd(&gh[b], v); }
}

// ---------------- K2: find bin containing the 1000th-largest score ----------------
__global__ __launch_bounds__(256) void k_scan(const unsigned* hist, unsigned* thi){
  int grp = blockIdx.x;
  const unsigned* gh = hist + (size_t)grp*NBIN;
  __shared__ unsigned part[256];
  unsigned ssum = 0;
  int base = threadIdx.x*16;
  for (int b = base; b < base+16; ++b) ssum += gh[b];
  part[threadIdx.x] = ssum;
  __syncthreads();
  if (threadIdx.x == 0){
    int k = PRE;
    int c = 255;
    while ((int)part[c] < k){ k -= (int)part[c]; --c; }
    int b = c*16 + 15;
    while ((int)gh[b] < k){ k -= (int)gh[b]; --b; }
    thi[grp] = (unsigned)b;
  }
}

// ---------------- K3: compact >bin elements (decode+key), collect ==bin candidates ----------------
__global__ __launch_bounds__(256) void k_compact(const float* o0,const float* o1,const float* o2,const float* o3,const float* o4,
                                                 const float* d0,const float* d1,const float* d2,const float* d3,const float* d4,
                                                 const float* anchors, const unsigned* thi,
                                                 unsigned* cnt_gt, unsigned* cnt_eq,
                                                 unsigned long long* cand, unsigned long long* keys){
  int grp = blockIdx.y; int n = grp/5, lvl = grp - n*5;
  const float* ob = sel5(lvl,o0,o1,o2,o3,o4);
  const float* dl = sel5(lvl,d0,d1,d2,d3,d4);
  int HW = c_HW[lvl], M = 3*HW;
  ob += (size_t)n*(size_t)M;
  unsigned T = thi[grp];
  unsigned long long* kout = keys + (size_t)n*K_SEL + (size_t)lvl*PRE;
  int stride = gridDim.x*256;
  for (int i = blockIdx.x*256 + threadIdx.x; i < M; i += stride){
    unsigned s = f2s(ob[i]);
    unsigned sh = s >> 20;
    if (sh > T){
      unsigned pos = atomicAdd(&cnt_gt[grp], 1u);
      int a = i / HW; int rem = i - a*HW; int t = rem*3 + a;
      kout[pos] = make_key(s, lvl, t, n, dl, anchors);
    } else if (sh == T){
      unsigned e = atomicAdd(&cnt_eq[grp], 1u);
      if (e < TIE_CAP){
        int a = i / HW; int rem = i - a*HW; int t = rem*3 + a;
        cand[(size_t)grp*TIE_CAP + e] = ((unsigned long long)(~s) << 19) | (unsigned long long)(unsigned)t;
      }
    }
  }
}

template<int SZ>
__device__ void bitonic(unsigned long long* sk){
  for (int k = 2; k <= SZ; k <<= 1){
    for (int j = k >> 1; j > 0; j >>= 1){
      for (int i = threadIdx.x; i < SZ; i += blockDim.x){
        int ix = i ^ j;
        if (ix > i){
          unsigned long long va = sk[i], vb = sk[ix];
          if ((va > vb) == ((i & k) == 0)){ sk[i] = vb; sk[ix] = va; }
        }
      }
      __syncthreads();
    }
  }
}

// runtime-sized bitonic (SZ uniform across block, power of 2)
__device__ void bitonic_rt(unsigned long long* sk, int SZ){
  for (int k = 2; k <= SZ; k <<= 1){
    for (int j = k >> 1; j > 0; j >>= 1){
      for (int i = threadIdx.x; i < SZ; i += blockDim.x){
        int ix = i ^ j;
        if (ix > i){
          unsigned long long va = sk[i], vb = sk[ix];
          if ((va > vb) == ((i & k) == 0)){ sk[i] = vb; sk[ix] = va; }
        }
      }
      __syncthreads();
    }
  }
}

// ---------------- K4: exact boundary selection within the threshold bin ----------------
__global__ __launch_bounds__(256) void k_tiesel(const float* d0,const float* d1,const float* d2,const float* d3,const float* d4,
                                                const float* anchors,
                                                const unsigned* cnt_gt, const unsigned* cnt_eq,
                                                const unsigned long long* cand, unsigned long long* keys){
  int grp = blockIdx.x; int n = grp/5, lvl = grp - n*5;
  __shared__ unsigned long long sk[TIE_CAP];
  int ne = min((int)cnt_eq[grp], TIE_CAP);
  int SZ = 64; while (SZ < ne) SZ <<= 1;    // runtime pow2 >= ne (uniform)
  for (int i = threadIdx.x; i < SZ; i += 256)
    sk[i] = (i < ne) ? cand[(size_t)grp*TIE_CAP + i] : ~0ULL;
  __syncthreads();
  bitonic_rt(sk, SZ);                // ascending: (score desc, idx asc)
  int cg = (int)cnt_gt[grp];
  int need = PRE - cg;
  const float* dl = sel5(lvl,d0,d1,d2,d3,d4);
  unsigned long long* kout = keys + (size_t)n*K_SEL + (size_t)lvl*PRE + cg;
  for (int j = threadIdx.x; j < need; j += 256){
    if (j < ne){
      unsigned long long ck = sk[j];
      unsigned t = (unsigned)(ck & 0x7FFFFu);
      unsigned s = ~((unsigned)(ck >> 19));
      kout[j] = make_key(s, lvl, (int)t, n, dl, anchors);
    } else {
      kout[j] = ((unsigned long long)(~S_NEGINF) << 22); // pathological overflow: harmless invalid
    }
  }
}

// ---------------- K5a: sort each (image,level) run; decode level-space arrays ----------------
__global__ __launch_bounds__(256) void k_sortlvl(unsigned long long* keys,
                                                 const float* d0,const float* d1,const float* d2,const float* d3,const float* d4,
                                                 const float* anchors,
                                                 float4* lbox, float4* lobox, float* loarea, float* lskey){
  int grp = blockIdx.x; int n = grp/5, lvl = grp - n*5;
  __shared__ unsigned long long sk[1024];
  unsigned long long* kp = keys + (size_t)n*K_SEL + (size_t)lvl*PRE;
  for (int i = threadIdx.x; i < 1024; i += 256)
    sk[i] = (i < PRE) ? kp[i] : ~0ULL;
  __syncthreads();
  bitonic<1024>(sk);
  const float* dl = sel5(lvl,d0,d1,d2,d3,d4);
  for (int i = threadIdx.x; i < PRE; i += 256){
    unsigned long long key = sk[i];
    kp[i] = key;                          // sorted run back to global (k_rank reads it)
    int t = (int)(key & 0x7FFFFu);
    unsigned se = ~((unsigned)(key >> 22));
    BoxV b = decode_box(lvl, t, n, dl, anchors);
    size_t o = (size_t)grp*PRE + i;
    lbox[o] = make_float4(b.x1,b.y1,b.x2,b.y2);
    lskey[o] = s2f(se);                   // -inf if invalid
    float off = (float)lvl * 1345.0f;     // (IMG+1) batched-NMS offset
    float ox1 = __fadd_rn(b.x1, off), oy1 = __fadd_rn(b.y1, off);
    float ox2 = __fadd_rn(b.x2, off), oy2 = __fadd_rn(b.y2, off);
    lobox[o] = make_float4(ox1,oy1,ox2,oy2);
    loarea[o] = __fmul_rn(__fsub_rn(ox2,ox1), __fsub_rn(oy2,oy1));
  }
}

// ---------------- K5b: global rank of each level element (keys globally unique) ----------------
// rankinfo[rank] = p | (lvl<<10) | (valid<<13)
__global__ __launch_bounds__(256) void k_rank(const unsigned long long* keys, unsigned* rankinfo){
  int grp = blockIdx.x; int n = grp/5, lvl = grp - n*5;
  __shared__ unsigned long long sl[K_SEL];
  for (int i = threadIdx.x; i < K_SEL; i += 256) sl[i] = keys[(size_t)n*K_SEL + i];
  __syncthreads();
  for (int j = threadIdx.x; j < PRE; j += 256){
    unsigned long long k = sl[lvl*PRE + j];
    int rank = j;
    #pragma unroll
    for (int m = 0; m < 5; ++m){
      if (m == lvl) continue;
      const unsigned long long* s = sl + m*PRE;
      int lo = 0, hi = PRE;
      while (lo < hi){ int mid = (lo+hi) >> 1; if (s[mid] < k) lo = mid+1; else hi = mid; }
      rank += lo;
    }
    unsigned se = ~((unsigned)(k >> 22));
    unsigned info = (unsigned)j | ((unsigned)lvl << 10) | ((se != S_NEGINF) ? (1u<<13) : 0u);
    rankinfo[(size_t)n*K_SEL + rank] = info;   // exact permutation of [0,5000)
  }
}

// ---------------- K6a: per-level suppression bit-matrix (block-diagonal; j>p) ----------------
__global__ __launch_bounds__(256) void k_ioumat_lvl(const float4* lobox, const float* loarea, unsigned* lmat){
  int grp = blockIdx.y;                  // n*5 + L
  int chunk = blockIdx.x;                // 4 chunks x 250 rows
  __shared__ float sx1[1024], sy1[1024], sx2[1024], sy2[1024], sar[1024];
  for (int i = threadIdx.x; i < 1024; i += 256){
    float4 bb = make_float4(0.f,0.f,0.f,0.f); float ar = 0.f;
    if (i < PRE){ bb = lobox[(size_t)grp*PRE + i]; ar = loarea[(size_t)grp*PRE + i]; }
    sx1[i]=bb.x; sy1[i]=bb.y; sx2[i]=bb.z; sy2[i]=bb.w; sar[i]=ar;
  }
  __syncthreads();
  int p0 = chunk*250;
  unsigned* mg = lmat + (size_t)grp*PRE*32;
  for (int task = threadIdx.x; task < 250*32; task += 256){
    int p = p0 + (task >> 5), w = task & 31;
    unsigned bits = 0u;
    if (w*32 + 31 > p){
      float bx1=sx1[p], by1=sy1[p], bx2=sx2[p], by2=sy2[p], ba=sar[p];  // broadcast (uniform per half-wave)
      #pragma unroll
      for (int jj = 0; jj < 32; ++jj){
        int js = (jj + w) & 31;          // per-lane rotation -> conflict-free LDS banks
        int j = (w<<5) + js;
        float ltx = fmaxf(bx1, sx1[j]), lty = fmaxf(by1, sy1[j]);
        float rbx = fminf(bx2, sx2[j]), rby = fminf(by2, sy2[j]);
        float ww_ = fmaxf(__fsub_rn(rbx,ltx), 0.0f);
        float hh_ = fmaxf(__fsub_rn(rby,lty), 0.0f);
        float inter = __fmul_rn(ww_,hh_);
        float uni = __fsub_rn(__fadd_rn(ba, sar[j]), inter);
        bool hit = (__fdiv_rn(inter,uni) > 0.7f) && (j > p);   // j>=1000 pad boxes give inter=0
        bits |= (hit ? 1u : 0u) << js;
      }
    }
    mg[(size_t)p*32 + w] = bits;
  }
}

// ---------------- K6b: greedy scan, one wave per image; level-space sup masks ----------------
__global__ __launch_bounds__(64) void k_scan_nms2(const unsigned* rankinfo, const unsigned* lmat,
                                                  const float4* lbox, const float* lskey, float* out){
  int n = blockIdx.x; int lane = threadIdx.x;
  int n5 = n*5;
  const unsigned* rin = rankinfo + (size_t)n*K_SEL;
  // sup word `lane` of each level lives in lanes 0-31 (lanes 32-63 hold junk; never read)
  unsigned sup0=0u,sup1=0u,sup2=0u,sup3=0u,sup4=0u;
  unsigned riC = rin[lane];
  unsigned riN = rin[64+lane];
  unsigned RA[16],RB[16],RC[16],RD[16];
  // one wave-wide load per candidate: lanes 0-31 row words, 32-35 box, 36+ score
#define LOADW(REG, rr, RI) { \
    int r_ = (rr); if (r_ > K_SEL-1) r_ = K_SEL-1; \
    unsigned info_ = __shfl((RI), r_ & 63); \
    int L_ = (info_ >> 10) & 7; int p_ = (int)(info_ & 1023u); \
    size_t idx_ = (size_t)(n5 + L_)*PRE + p_; \
    const unsigned* ap_; \
    if (lane < 32)      ap_ = lmat + idx_*32 + lane; \
    else if (lane < 36) ap_ = (const unsigned*)lbox + idx_*4 + (lane-32); \
    else                ap_ = (const unsigned*)lskey + idx_; \
    REG = *ap_; }
#define PROC(REG, ii, RI) { \
    int i_ = (ii); \
    if (i_ < K_SEL && kept < PRE){ \
      unsigned info_ = __shfl((RI), i_ & 63); \
      if (info_ & (1u<<13)){ \
        int L_ = (info_ >> 10) & 7; int p_ = (int)(info_ & 1023u); \
        unsigned myS_ = (L_==0)?sup0:(L_==1)?sup1:(L_==2)?sup2:(L_==3)?sup3:sup4; \
        unsigned sw_ = __shfl(myS_, p_ >> 5); \
        if (!((sw_ >> (p_ & 31)) & 1u)){ \
          switch(L_){ case 0: sup0|=REG; break; case 1: sup1|=REG; break; \
                      case 2: sup2|=REG; break; case 3: sup3|=REG; break; default: sup4|=REG; } \
          if (lane >= 32 && lane < 37) outn[(size_t)kept*5 + (lane-32)] = __uint_as_float(REG); \
          ++kept; \
        } \
      } \
    } }
  #pragma unroll
  for (int d=0; d<16; ++d) LOADW(RA[d], d, riC);
  #pragma unroll
  for (int d=0; d<16; ++d) LOADW(RB[d], 16+d, riC);
  #pragma unroll
  for (int d=0; d<16; ++d) LOADW(RC[d], 32+d, riC);
  #pragma unroll
  for (int d=0; d<16; ++d) LOADW(RD[d], 48+d, riC);
  int kept = 0;
  float* outn = out + (size_t)n*PRE*5;
  for (int base = 0; base < K_SEL; base += 64){
    #pragma unroll
    for (int d=0; d<16; ++d) PROC(RA[d], base+d, riC);
    if (kept >= PRE) break;
    #pragma unroll
    for (int d=0; d<16; ++d) LOADW(RA[d], base+64+d, riN);
    #pragma unroll
    for (int d=0; d<16; ++d) PROC(RB[d], base+16+d, riC);
    if (kept >= PRE) break;
    #pragma unroll
    for (int d=0; d<16; ++d) LOADW(RB[d], base+80+d, riN);
    #pragma unroll
    for (int d=0; d<16; ++d) PROC(RC[d], base+32+d, riC);
    if (kept >= PRE) break;
    #pragma unroll
    for (int d=0; d<16; ++d) LOADW(RC[d], base+96+d, riN);
    #pragma unroll
    for (int d=0; d<16; ++d) PROC(RD[d], base+48+d, riC);
    if (kept >= PRE) break;
    #pragma unroll
    for (int d=0; d<16; ++d) LOADW(RD[d], base+112+d, riN);
    riC = riN;
    int nx = base + 128 + lane; if (nx > K_SEL-1) nx = K_SEL-1;
    riN = rin[nx];
  }
#undef LOADW
#undef PROC
}

// ---------------- fallback path (ws too small): round-3 kernels ----------------
__global__ __launch_bounds__(256) void k_sortimg(const unsigned long long* keys,
                                                 const float* d0,const float* d1,const float* d2,const float* d3,const float* d4,
                                                 const float* anchors,
                                                 float4* sbox, float* sskey, int* slvl){
  int n = blockIdx.x;
  __shared__ unsigned long long sk[8192];
  for (int i = threadIdx.x; i < 8192; i += 256)
    sk[i] = (i < K_SEL) ? keys[(size_t)n*K_SEL + i] : ~0ULL;
  __syncthreads();
  bitonic<8192>(sk);
  for (int r = threadIdx.x; r < K_SEL; r += 256){
    unsigned long long key = sk[r];
    int t = (int)(key & 0x7FFFFu);
    int lvl = (int)((key >> 19) & 7u);
    unsigned se = ~((unsigned)(key >> 22));
    const float* dl = sel5(lvl,d0,d1,d2,d3,d4);
    BoxV b = decode_box(lvl, t, n, dl, anchors);
    sbox[(size_t)n*K_SEL + r] = make_float4(b.x1,b.y1,b.x2,b.y2);
    sskey[(size_t)n*K_SEL + r] = s2f(se);
    slvl[(size_t)n*K_SEL + r] = lvl;
  }
}

__global__ __launch_bounds__(256) void k_nms(const float4* sbox, const float* sskey, const int* slvl, float* out){
  int n = blockIdx.x, tid = threadIdx.x;
  __shared__ float kx1[PRE], ky1[PRE], kx2[PRE], ky2[PRE], kar[PRE];
  __shared__ int klv[PRE];
  __shared__ int nv_s, flag_s;
  for (int i = tid; i < PRE*5; i += 256) out[(size_t)n*PRE*5 + i] = 0.0f;
  if (tid == 0){ nv_s = 0; flag_s = 0; }
  __syncthreads();
  int c = 0;
  for (int i = tid; i < K_SEL; i += 256)
    if (sskey[(size_t)n*K_SEL + i] != -INFINITY) ++c;
  atomicAdd(&nv_s, c);
  __syncthreads();
  int nvalid = nv_s;
  int kept = 0;
  for (int i = 0; i < nvalid; ++i){
    float4 b = sbox[(size_t)n*K_SEL + i];
    int lv = slvl[(size_t)n*K_SEL + i];
    float off = (float)lv * 1345.0f;
    float ox1 = __fadd_rn(b.x, off), oy1 = __fadd_rn(b.y, off);
    float ox2 = __fadd_rn(b.z, off), oy2 = __fadd_rn(b.w, off);
    float area = __fmul_rn(__fsub_rn(ox2,ox1), __fsub_rn(oy2,oy1));
    bool hit = false;
    for (int j = tid; j < kept; j += 256){
      if (klv[j] == lv){
        float ltx = fmaxf(kx1[j], ox1), lty = fmaxf(ky1[j], oy1);
        float rbx = fminf(kx2[j], ox2), rby = fminf(ky2[j], oy2);
        float w = fmaxf(__fsub_rn(rbx,ltx), 0.0f);
        float h = fmaxf(__fsub_rn(rby,lty), 0.0f);
        float inter = __fmul_rn(w,h);
        float uni = __fsub_rn(__fadd_rn(kar[j], area), inter);
        if (__fdiv_rn(inter,uni) > 0.7f) hit = true;
      }
    }
    if (hit) flag_s = 1;
    __syncthreads();
    int sup = flag_s;
    __syncthreads();
    if (!sup){
      if (tid == 0){
        kx1[kept]=ox1; ky1[kept]=oy1; kx2[kept]=ox2; ky2[kept]=oy2; kar[kept]=area; klv[kept]=lv;
        float* orow = out + (size_t)n*PRE*5 + (size_t)kept*5;
        orow[0]=b.x; orow[1]=b.y; orow[2]=b.z; orow[3]=b.w;
        orow[4]=sskey[(size_t)n*K_SEL + i];
      }
      ++kept;
    }
    if (tid == 0) flag_s = 0;
    __syncthreads();
    if (kept == PRE) break;
  }
}

extern "C" void kernel_launch(void* const* d_in, const int* in_sizes, int n_in,
                              void* d_out, int out_size, void* d_ws, size_t ws_size,
                              hipStream_t stream) {
  bool interleaved = (in_sizes[1] == 4*in_sizes[0]);
  const float* obj[5]; const float* dlt[5];
  for (int i = 0; i < 5; ++i){
    if (interleaved){ obj[i] = (const float*)d_in[2*i]; dlt[i] = (const float*)d_in[2*i+1]; }
    else            { obj[i] = (const float*)d_in[i];   dlt[i] = (const float*)d_in[5+i]; }
  }
  const float* anchors = (const float*)d_in[10];

  char* ws = (char*)d_ws;
  unsigned* hist            = (unsigned*)(ws);                     // 655360
  unsigned* cnt_gt          = (unsigned*)(ws + 655360);            // 160
  unsigned* cnt_eq          = (unsigned*)(ws + 655520);            // 160
  unsigned* thi             = (unsigned*)(ws + 655680);            // 160 -> counters end 655840
  unsigned long long* cand  = (unsigned long long*)(ws + 655840);  // 1310720 -> 1966560
  unsigned long long* keys  = (unsigned long long*)(ws + 1966560); // 320000 -> 2286560
  float4* lbox              = (float4*)(ws + 2286560);             // 640000 -> 2926560
  float4* lobox             = (float4*)(ws + 2926560);             // 640000 -> 3566560
  float* loarea             = (float*)(ws + 3566560);              // 160000 -> 3726560
  float* lskey              = (float*)(ws + 3726560);              // 160000 -> 3886560
  unsigned* rankinfo        = (unsigned*)(ws + 3886560);           // 160000 -> 4046560
  unsigned* lmat            = (unsigned*)(ws + 4046560);           // 5120000 -> 9166560
  float4* sbox              = (float4*)(ws + 9166560);             // fallback: 640000 -> 9806560
  float* sskey              = (float*)(ws + 9806560);              // 160000 -> 9966560
  int* slvl                 = (int*)(ws + 9966560);                // 160000 -> 10126560
  const size_t NEED = 10126560;

  hipMemsetAsync(ws, 0, 655840, stream);   // hist + counters

  dim3 gScan(8, 40);
  k_hist<<<gScan, 256, 0, stream>>>(obj[0],obj[1],obj[2],obj[3],obj[4], hist);
  k_scan<<<40, 256, 0, stream>>>(hist, thi);
  k_compact<<<gScan, 256, 0, stream>>>(obj[0],obj[1],obj[2],obj[3],obj[4],
                                       dlt[0],dlt[1],dlt[2],dlt[3],dlt[4],
                                       anchors, thi, cnt_gt, cnt_eq, cand, keys);
  k_tiesel<<<40, 256, 0, stream>>>(dlt[0],dlt[1],dlt[2],dlt[3],dlt[4], anchors,
                                   cnt_gt, cnt_eq, cand, keys);
  if (ws_size >= NEED){
    k_sortlvl<<<40, 256, 0, stream>>>(keys, dlt[0],dlt[1],dlt[2],dlt[3],dlt[4], anchors,
                                      lbox, lobox, loarea, lskey);
    k_rank<<<40, 256, 0, stream>>>(keys, rankinfo);
    k_ioumat_lvl<<<dim3(4, 40), 256, 0, stream>>>(lobox, loarea, lmat);
    hipMemsetAsync(d_out, 0, (size_t)out_size*sizeof(float), stream);
    k_scan_nms2<<<8, 64, 0, stream>>>(rankinfo, lmat, lbox, lskey, (float*)d_out);
  } else {
    k_sortimg<<<8, 256, 0, stream>>>(keys, dlt[0],dlt[1],dlt[2],dlt[3],dlt[4], anchors,
                                     sbox, sskey, slvl);
    k_nms<<<8, 256, 0, stream>>>(sbox, sskey, slvl, (float*)d_out);
  }
}

// Round 6
// 637.908 us; speedup vs baseline: 1.2685x; 1.2685x over previous
//
#include <hip/hip_runtime.h>
#include <cmath>

#define N_IMG   8
#define PRE     1000
#define K_SEL   5000
#define NBIN    4096
#define TIE_CAP 4096
#define IMG_F   1344.0f
#define S_NEGINF 0x007FFFFFu
#define TILES   79             // ceil(5000/64)

__constant__ int c_W[5]   = {336,168,84,42,21};
__constant__ int c_HW[5]  = {112896,28224,7056,1764,441};
__constant__ int c_OFF[5] = {0,338688,423360,444528,449820};

__device__ __forceinline__ unsigned f2s(float f){
  unsigned u = __float_as_uint(f);
  return (u & 0x80000000u) ? ~u : (u | 0x80000000u);
}
__device__ __forceinline__ float s2f(unsigned s){
  unsigned u = (s & 0x80000000u) ? (s & 0x7FFFFFFFu) : ~s;
  return __uint_as_float(u);
}
__device__ __forceinline__ const float* sel5(int l, const float* p0,const float* p1,const float* p2,const float* p3,const float* p4){
  switch(l){case 0:return p0;case 1:return p1;case 2:return p2;case 3:return p3;default:return p4;}
}

struct BoxV { float x1,y1,x2,y2; bool valid; };

// Bit-faithful torchvision BoxCoder.decode + clip + min-size validity.
__device__ BoxV decode_box(int lvl, int t, int n, const float* dl, const float* anchors){
  int HW = c_HW[lvl], W = c_W[lvl];
  int a = t % 3, pos = t / 3;          // t = (h*W+w)*3 + a
  int h = pos / W, w = pos - h*W;
  int g = c_OFF[lvl] + t;
  const float* an = anchors + (size_t)4*(size_t)g;
  float a0=an[0], a1=an[1], a2=an[2], a3=an[3];
  float aw = __fsub_rn(a2,a0), ah = __fsub_rn(a3,a1);
  float acx = __fadd_rn(a0, __fmul_rn(0.5f,aw));
  float acy = __fadd_rn(a1, __fmul_rn(0.5f,ah));
  const float* dp = dl + ((size_t)n*12 + (size_t)a*4)*(size_t)HW + (size_t)h*W + (size_t)w;
  float dx = dp[0], dy = dp[HW], dwv = dp[2*(size_t)HW], dhv = dp[3*(size_t)HW];
  const float CLAMP = (float)4.135166556742356;  // log(1000/16)
  dwv = fminf(dwv, CLAMP); dhv = fminf(dhv, CLAMP);
  float pcx = __fadd_rn(__fmul_rn(dx,aw), acx);
  float pcy = __fadd_rn(__fmul_rn(dy,ah), acy);
  float pw = __fmul_rn((float)::exp((double)dwv), aw);
  float ph = __fmul_rn((float)::exp((double)dhv), ah);
  float hx = __fmul_rn(0.5f,pw), hy = __fmul_rn(0.5f,ph);
  BoxV b;
  b.x1 = fminf(fmaxf(__fsub_rn(pcx,hx),0.0f),IMG_F);
  b.y1 = fminf(fmaxf(__fsub_rn(pcy,hy),0.0f),IMG_F);
  b.x2 = fminf(fmaxf(__fadd_rn(pcx,hx),0.0f),IMG_F);
  b.y2 = fminf(fmaxf(__fadd_rn(pcy,hy),0.0f),IMG_F);
  b.valid = (__fsub_rn(b.x2,b.x1) >= 1e-3f) && (__fsub_rn(b.y2,b.y1) >= 1e-3f);
  return b;
}

// key = (~s_eff)<<22 | lvl<<19 | t : ascending sort == (score desc, level asc, idx asc)
__device__ unsigned long long make_key(unsigned s, int lvl, int t, int n, const float* dl, const float* anchors){
  BoxV b = decode_box(lvl,t,n,dl,anchors);
  unsigned se = b.valid ? s : S_NEGINF;     // invalid -> skey = -inf
  return ((unsigned long long)(~se) << 22) | ((unsigned long long)(unsigned)lvl << 19) | (unsigned long long)(unsigned)t;
}

// ---------------- K1: per-(image,level) 12-bit score histogram ----------------
__global__ __launch_bounds__(256) void k_hist(const float* o0,const float* o1,const float* o2,const float* o3,const float* o4,
                                              unsigned* hist){
  int grp = blockIdx.y; int n = grp/5, lvl = grp - n*5;
  const float* ob = sel5(lvl,o0,o1,o2,o3,o4);
  int HW = c_HW[lvl], M = 3*HW;
  ob += (size_t)n*(size_t)M;
  __shared__ unsigned lh[NBIN];
  for (int b = threadIdx.x; b < NBIN; b += 256) lh[b] = 0;
  __syncthreads();
  int stride = gridDim.x*256;
  for (int i = blockIdx.x*256 + threadIdx.x; i < M; i += stride){
    unsigned s = f2s(ob[i]);
    atomicAdd(&lh[s >> 20], 1u);
  }
  __syncthreads();
  unsigned* gh = hist + (size_t)grp*NBIN;
  for (int b = threadIdx.x; b < NBIN; b += 256){ unsigned v = lh[b]; if (v) atomicAdd(&gh[b], v); }
}

// ---------------- K2: find bin containing the 1000th-largest score ----------------
__global__ __launch_bounds__(256) void k_scan(const unsigned* hist, unsigned* thi){
  int grp = blockIdx.x;
  const unsigned* gh = hist + (size_t)grp*NBIN;
  __shared__ unsigned part[256];
  unsigned ssum = 0;
  int base = threadIdx.x*16;
  for (int b = base; b < base+16; ++b) ssum += gh[b];
  part[threadIdx.x] = ssum;
  __syncthreads();
  if (threadIdx.x == 0){
    int k = PRE;
    int c = 255;
    while ((int)part[c] < k){ k -= (int)part[c]; --c; }
    int b = c*16 + 15;
    while ((int)gh[b] < k){ k -= (int)gh[b]; --b; }
    thi[grp] = (unsigned)b;
  }
}

// ---------------- K3: compact >bin elements (decode+key), collect ==bin candidates ----------------
__global__ __launch_bounds__(256) void k_compact(const float* o0,const float* o1,const float* o2,const float* o3,const float* o4,
                                                 const float* d0,const float* d1,const float* d2,const float* d3,const float* d4,
                                                 const float* anchors, const unsigned* thi,
                                                 unsigned* cnt_gt, unsigned* cnt_eq,
                                                 unsigned long long* cand, unsigned long long* keys){
  int grp = blockIdx.y; int n = grp/5, lvl = grp - n*5;
  const float* ob = sel5(lvl,o0,o1,o2,o3,o4);
  const float* dl = sel5(lvl,d0,d1,d2,d3,d4);
  int HW = c_HW[lvl], M = 3*HW;
  ob += (size_t)n*(size_t)M;
  unsigned T = thi[grp];
  unsigned long long* kout = keys + (size_t)n*K_SEL + (size_t)lvl*PRE;
  int stride = gridDim.x*256;
  for (int i = blockIdx.x*256 + threadIdx.x; i < M; i += stride){
    unsigned s = f2s(ob[i]);
    unsigned sh = s >> 20;
    if (sh > T){
      unsigned pos = atomicAdd(&cnt_gt[grp], 1u);
      int a = i / HW; int rem = i - a*HW; int t = rem*3 + a;
      kout[pos] = make_key(s, lvl, t, n, dl, anchors);
    } else if (sh == T){
      unsigned e = atomicAdd(&cnt_eq[grp], 1u);
      if (e < TIE_CAP){
        int a = i / HW; int rem = i - a*HW; int t = rem*3 + a;
        cand[(size_t)grp*TIE_CAP + e] = ((unsigned long long)(~s) << 19) | (unsigned long long)(unsigned)t;
      }
    }
  }
}

template<int SZ>
__device__ void bitonic(unsigned long long* sk){
  for (int k = 2; k <= SZ; k <<= 1){
    for (int j = k >> 1; j > 0; j >>= 1){
      for (int i = threadIdx.x; i < SZ; i += blockDim.x){
        int ix = i ^ j;
        if (ix > i){
          unsigned long long va = sk[i], vb = sk[ix];
          if ((va > vb) == ((i & k) == 0)){ sk[i] = vb; sk[ix] = va; }
        }
      }
      __syncthreads();
    }
  }
}

// runtime-sized bitonic (SZ uniform across block, power of 2)
__device__ void bitonic_rt(unsigned long long* sk, int SZ){
  for (int k = 2; k <= SZ; k <<= 1){
    for (int j = k >> 1; j > 0; j >>= 1){
      for (int i = threadIdx.x; i < SZ; i += blockDim.x){
        int ix = i ^ j;
        if (ix > i){
          unsigned long long va = sk[i], vb = sk[ix];
          if ((va > vb) == ((i & k) == 0)){ sk[i] = vb; sk[ix] = va; }
        }
      }
      __syncthreads();
    }
  }
}

// ---------------- K4: exact boundary selection within the threshold bin ----------------
__global__ __launch_bounds__(256) void k_tiesel(const float* d0,const float* d1,const float* d2,const float* d3,const float* d4,
                                                const float* anchors,
                                                const unsigned* cnt_gt, const unsigned* cnt_eq,
                                                const unsigned long long* cand, unsigned long long* keys){
  int grp = blockIdx.x; int n = grp/5, lvl = grp - n*5;
  __shared__ unsigned long long sk[TIE_CAP];
  int ne = min((int)cnt_eq[grp], TIE_CAP);
  int SZ = 64; while (SZ < ne) SZ <<= 1;    // runtime pow2 >= ne (uniform)
  for (int i = threadIdx.x; i < SZ; i += 256)
    sk[i] = (i < ne) ? cand[(size_t)grp*TIE_CAP + i] : ~0ULL;
  __syncthreads();
  bitonic_rt(sk, SZ);                // ascending: (score desc, idx asc)
  int cg = (int)cnt_gt[grp];
  int need = PRE - cg;
  const float* dl = sel5(lvl,d0,d1,d2,d3,d4);
  unsigned long long* kout = keys + (size_t)n*K_SEL + (size_t)lvl*PRE + cg;
  for (int j = threadIdx.x; j < need; j += 256){
    if (j < ne){
      unsigned long long ck = sk[j];
      unsigned t = (unsigned)(ck & 0x7FFFFu);
      unsigned s = ~((unsigned)(ck >> 19));
      kout[j] = make_key(s, lvl, (int)t, n, dl, anchors);
    } else {
      kout[j] = ((unsigned long long)(~S_NEGINF) << 22); // pathological overflow: harmless invalid
    }
  }
}

// ---------------- K5a: sort each (image,level) run; decode level-space arrays ----------------
__global__ __launch_bounds__(256) void k_sortlvl(unsigned long long* keys,
                                                 const float* d0,const float* d1,const float* d2,const float* d3,const float* d4,
                                                 const float* anchors,
                                                 float4* lbox, float4* lobox, float* loarea, float* lskey){
  int grp = blockIdx.x; int n = grp/5, lvl = grp - n*5;
  __shared__ unsigned long long sk[1024];
  unsigned long long* kp = keys + (size_t)n*K_SEL + (size_t)lvl*PRE;
  for (int i = threadIdx.x; i < 1024; i += 256)
    sk[i] = (i < PRE) ? kp[i] : ~0ULL;
  __syncthreads();
  bitonic<1024>(sk);
  const float* dl = sel5(lvl,d0,d1,d2,d3,d4);
  for (int i = threadIdx.x; i < PRE; i += 256){
    unsigned long long key = sk[i];
    kp[i] = key;                          // sorted run back to global (k_rank reads it)
    int t = (int)(key & 0x7FFFFu);
    unsigned se = ~((unsigned)(key >> 22));
    BoxV b = decode_box(lvl, t, n, dl, anchors);
    size_t o = (size_t)grp*PRE + i;
    lbox[o] = make_float4(b.x1,b.y1,b.x2,b.y2);
    lskey[o] = s2f(se);                   // -inf if invalid
    float off = (float)lvl * 1345.0f;     // (IMG+1) batched-NMS offset
    float ox1 = __fadd_rn(b.x1, off), oy1 = __fadd_rn(b.y1, off);
    float ox2 = __fadd_rn(b.x2, off), oy2 = __fadd_rn(b.y2, off);
    lobox[o] = make_float4(ox1,oy1,ox2,oy2);
    loarea[o] = __fmul_rn(__fsub_rn(ox2,ox1), __fsub_rn(oy2,oy1));
  }
}

// ---------------- K5b: global rank of each level element (keys globally unique) ----------------
// rankinfo[rank] = p | (lvl<<10) | (valid<<13)
__global__ __launch_bounds__(256) void k_rank(const unsigned long long* keys, unsigned* rankinfo){
  int grp = blockIdx.x; int n = grp/5, lvl = grp - n*5;
  __shared__ unsigned long long sl[K_SEL];
  for (int i = threadIdx.x; i < K_SEL; i += 256) sl[i] = keys[(size_t)n*K_SEL + i];
  __syncthreads();
  for (int j = threadIdx.x; j < PRE; j += 256){
    unsigned long long k = sl[lvl*PRE + j];
    int rank = j;
    #pragma unroll
    for (int m = 0; m < 5; ++m){
      if (m == lvl) continue;
      const unsigned long long* s = sl + m*PRE;
      int lo = 0, hi = PRE;
      while (lo < hi){ int mid = (lo+hi) >> 1; if (s[mid] < k) lo = mid+1; else hi = mid; }
      rank += lo;
    }
    unsigned se = ~((unsigned)(k >> 22));
    unsigned info = (unsigned)j | ((unsigned)lvl << 10) | ((se != S_NEGINF) ? (1u<<13) : 0u);
    rankinfo[(size_t)n*K_SEL + rank] = info;   // exact permutation of [0,5000)
  }
}

// ---------------- K6a: per-level suppression bit-matrix (block-diagonal; j>p) ----------------
__global__ __launch_bounds__(256) void k_ioumat_lvl(const float4* lobox, const float* loarea, unsigned* lmat){
  int grp = blockIdx.y;                  // n*5 + L
  int chunk = blockIdx.x;                // 4 chunks x 250 rows
  __shared__ float sx1[1024], sy1[1024], sx2[1024], sy2[1024], sar[1024];
  for (int i = threadIdx.x; i < 1024; i += 256){
    float4 bb = make_float4(0.f,0.f,0.f,0.f); float ar = 0.f;
    if (i < PRE){ bb = lobox[(size_t)grp*PRE + i]; ar = loarea[(size_t)grp*PRE + i]; }
    sx1[i]=bb.x; sy1[i]=bb.y; sx2[i]=bb.z; sy2[i]=bb.w; sar[i]=ar;
  }
  __syncthreads();
  int p0 = chunk*250;
  unsigned* mg = lmat + (size_t)grp*PRE*32;
  for (int task = threadIdx.x; task < 250*32; task += 256){
    int p = p0 + (task >> 5), w = task & 31;
    unsigned bits = 0u;
    if (w*32 + 31 > p){
      float bx1=sx1[p], by1=sy1[p], bx2=sx2[p], by2=sy2[p], ba=sar[p];
      #pragma unroll
      for (int jj = 0; jj < 32; ++jj){
        int js = (jj + w) & 31;          // per-lane rotation -> conflict-free LDS banks
        int j = (w<<5) + js;
        float ltx = fmaxf(bx1, sx1[j]), lty = fmaxf(by1, sy1[j]);
        float rbx = fminf(bx2, sx2[j]), rby = fminf(by2, sy2[j]);
        float ww_ = fmaxf(__fsub_rn(rbx,ltx), 0.0f);
        float hh_ = fmaxf(__fsub_rn(rby,lty), 0.0f);
        float inter = __fmul_rn(ww_,hh_);
        float uni = __fsub_rn(__fadd_rn(ba, sar[j]), inter);
        bool hit = (__fdiv_rn(inter,uni) > 0.7f) && (j > p);   // j>=1000 pad boxes give inter=0
        bits |= (hit ? 1u : 0u) << js;
      }
    }
    mg[(size_t)p*32 + w] = bits;
  }
}

// ---------------- K6b: tile-parallel greedy scan, one wave per image ----------------
// Tile of 64 candidates: parallel bpermute matrix build + ballot pre-suppression,
// scalar-only (readlane/SALU) 64-step greedy core, parallel output. No stores or
// gathers on the serial chain.
__global__ __launch_bounds__(64) void k_scan_nms3(const unsigned* rankinfo, const unsigned* lmat,
                                                  const float4* lbox, const float* lskey, float* out){
  int n = blockIdx.x; int lane = threadIdx.x;
  int n5 = n*5;
  const unsigned* rin = rankinfo + (size_t)n*K_SEL;
  float* outn = out + (size_t)n*PRE*5;
  // sup state: word (lane&31) of each level, duplicated in both half-waves
  unsigned sup0=0u,sup1=0u,sup2=0u,sup3=0u,sup4=0u;
  int kept_total = 0;
  unsigned RA[32], RB[32];
  float4 boxA, boxB; float scA = 0.f, scB = 0.f;
  unsigned infoA, infoB;

#define TLOAD(RS, BOX, SC, INFO) { \
    unsigned L_ = (INFO>>10)&7u; unsigned p_ = INFO & 1023u; \
    unsigned rowbase_ = (((unsigned)(n5) + L_)*PRE + p_) << 5; \
    _Pragma("unroll") \
    for (int d_=0; d_<32; ++d_){ \
      unsigned rb_ = __shfl(rowbase_, 2*d_ + (lane>>5)); \
      RS[d_] = lmat[(size_t)rb_ + (unsigned)(lane&31)]; \
    } \
    size_t bi_ = (size_t)((unsigned)(n5) + L_)*PRE + p_; \
    BOX = lbox[bi_]; SC = lskey[bi_]; \
  }

#define TPROC(RS, BOX, SC, INFO, baseexpr) { \
    int base_ = (baseexpr); \
    unsigned L_ = (INFO>>10)&7u; unsigned p_ = INFO & 1023u; \
    bool ok_ = (((INFO>>13)&1u) != 0u) && (base_ + lane < K_SEL); \
    int idxw_ = (int)(p_ >> 5); \
    unsigned t0_=__shfl(sup0,idxw_), t1_=__shfl(sup1,idxw_), t2_=__shfl(sup2,idxw_), t3_=__shfl(sup3,idxw_), t4_=__shfl(sup4,idxw_); \
    unsigned sw_ = (L_==0u)?t0_:(L_==1u)?t1_:(L_==2u)?t2_:(L_==3u)?t3_:t4_; \
    bool pre_ = (!ok_) || (((sw_ >> (p_&31)) & 1u) != 0u); \
    unsigned long long preM_ = __ballot(pre_); \
    unsigned cmlo_ = 0u, cmhi_ = 0u; \
    _Pragma("unroll") \
    for (int l_=0; l_<64; ++l_){ \
      unsigned infoL_ = __builtin_amdgcn_readlane(INFO, l_); \
      unsigned Ll_ = (infoL_>>10)&7u; \
      unsigned w_ = __shfl(RS[l_>>1], idxw_ + ((l_&1)<<5)); \
      unsigned bit_ = (w_ >> (p_&31)) & 1u; \
      bit_ &= (L_ == Ll_) ? 1u : 0u; \
      if (l_ < 32) cmlo_ |= bit_ << l_; else cmhi_ |= bit_ << (l_-32); \
    } \
    unsigned long long keptM_ = 0ull; \
    _Pragma("unroll") \
    for (int l_=0; l_<64; ++l_){ \
      unsigned long long cml_ = ((unsigned long long)__builtin_amdgcn_readlane(cmhi_, l_) << 32) \
                              |  (unsigned long long)__builtin_amdgcn_readlane(cmlo_, l_); \
      bool keep_ = (((preM_>>l_)&1ull) == 0ull) && ((cml_ & keptM_) == 0ull); \
      if (keep_) keptM_ |= (1ull<<l_); \
    } \
    _Pragma("unroll") \
    for (int l_=0; l_<64; ++l_){ \
      if ((keptM_>>l_)&1ull){ \
        unsigned infoL_ = __builtin_amdgcn_readlane(INFO, l_); \
        unsigned Ll_ = (infoL_>>10)&7u; \
        unsigned contrib_ = ((lane>>5) == (l_&1)) ? RS[l_>>1] : 0u; \
        switch(Ll_){ case 0u: sup0|=contrib_; break; case 1u: sup1|=contrib_; break; \
                     case 2u: sup2|=contrib_; break; case 3u: sup3|=contrib_; break; default: sup4|=contrib_; } \
      } \
    } \
    sup0 |= __shfl_xor(sup0,32); sup1 |= __shfl_xor(sup1,32); sup2 |= __shfl_xor(sup2,32); \
    sup3 |= __shfl_xor(sup3,32); sup4 |= __shfl_xor(sup4,32); \
    int pos_ = kept_total + (int)__popcll(keptM_ & ((1ull<<lane)-1ull)); \
    if (((keptM_>>lane)&1ull) && pos_ < PRE){ \
      float* orow_ = outn + (size_t)pos_*5; \
      orow_[0]=BOX.x; orow_[1]=BOX.y; orow_[2]=BOX.z; orow_[3]=BOX.w; orow_[4]=SC; \
    } \
    kept_total += (int)__popcll(keptM_); \
  }

  infoA = rin[lane];                       // tile 0 info
  TLOAD(RA, boxA, scA, infoA);             // tile 0 rows/box/score
  infoB = rin[64 + lane];                  // tile 1 info

  for (int t = 0; t < TILES; t += 2){
    // even tile t: process A, prefetch tile t+1 into B
    if (t+1 < TILES) TLOAD(RB, boxB, scB, infoB);
    TPROC(RA, boxA, scA, infoA, t*64);
    if (kept_total >= PRE) break;
    if (t+2 < TILES){ int cn=(t+2)*64+lane; if(cn>K_SEL-1)cn=K_SEL-1; infoA = rin[cn]; }
    // odd tile t+1: process B, prefetch tile t+2 into A
    if (t+1 < TILES){
      if (t+2 < TILES) TLOAD(RA, boxA, scA, infoA);
      TPROC(RB, boxB, scB, infoB, (t+1)*64);
      if (kept_total >= PRE) break;
      if (t+3 < TILES){ int cn=(t+3)*64+lane; if(cn>K_SEL-1)cn=K_SEL-1; infoB = rin[cn]; }
    }
  }
#undef TLOAD
#undef TPROC
}

// ---------------- fallback path (ws too small): round-3 kernels ----------------
__global__ __launch_bounds__(256) void k_sortimg(const unsigned long long* keys,
                                                 const float* d0,const float* d1,const float* d2,const float* d3,const float* d4,
                                                 const float* anchors,
                                                 float4* sbox, float* sskey, int* slvl){
  int n = blockIdx.x;
  __shared__ unsigned long long sk[8192];
  for (int i = threadIdx.x; i < 8192; i += 256)
    sk[i] = (i < K_SEL) ? keys[(size_t)n*K_SEL + i] : ~0ULL;
  __syncthreads();
  bitonic<8192>(sk);
  for (int r = threadIdx.x; r < K_SEL; r += 256){
    unsigned long long key = sk[r];
    int t = (int)(key & 0x7FFFFu);
    int lvl = (int)((key >> 19) & 7u);
    unsigned se = ~((unsigned)(key >> 22));
    const float* dl = sel5(lvl,d0,d1,d2,d3,d4);
    BoxV b = decode_box(lvl, t, n, dl, anchors);
    sbox[(size_t)n*K_SEL + r] = make_float4(b.x1,b.y1,b.x2,b.y2);
    sskey[(size_t)n*K_SEL + r] = s2f(se);
    slvl[(size_t)n*K_SEL + r] = lvl;
  }
}

__global__ __launch_bounds__(256) void k_nms(const float4* sbox, const float* sskey, const int* slvl, float* out){
  int n = blockIdx.x, tid = threadIdx.x;
  __shared__ float kx1[PRE], ky1[PRE], kx2[PRE], ky2[PRE], kar[PRE];
  __shared__ int klv[PRE];
  __shared__ int nv_s, flag_s;
  for (int i = tid; i < PRE*5; i += 256) out[(size_t)n*PRE*5 + i] = 0.0f;
  if (tid == 0){ nv_s = 0; flag_s = 0; }
  __syncthreads();
  int c = 0;
  for (int i = tid; i < K_SEL; i += 256)
    if (sskey[(size_t)n*K_SEL + i] != -INFINITY) ++c;
  atomicAdd(&nv_s, c);
  __syncthreads();
  int nvalid = nv_s;
  int kept = 0;
  for (int i = 0; i < nvalid; ++i){
    float4 b = sbox[(size_t)n*K_SEL + i];
    int lv = slvl[(size_t)n*K_SEL + i];
    float off = (float)lv * 1345.0f;
    float ox1 = __fadd_rn(b.x, off), oy1 = __fadd_rn(b.y, off);
    float ox2 = __fadd_rn(b.z, off), oy2 = __fadd_rn(b.w, off);
    float area = __fmul_rn(__fsub_rn(ox2,ox1), __fsub_rn(oy2,oy1));
    bool hit = false;
    for (int j = tid; j < kept; j += 256){
      if (klv[j] == lv){
        float ltx = fmaxf(kx1[j], ox1), lty = fmaxf(ky1[j], oy1);
        float rbx = fminf(kx2[j], ox2), rby = fminf(ky2[j], oy2);
        float w = fmaxf(__fsub_rn(rbx,ltx), 0.0f);
        float h = fmaxf(__fsub_rn(rby,lty), 0.0f);
        float inter = __fmul_rn(w,h);
        float uni = __fsub_rn(__fadd_rn(kar[j], area), inter);
        if (__fdiv_rn(inter,uni) > 0.7f) hit = true;
      }
    }
    if (hit) flag_s = 1;
    __syncthreads();
    int sup = flag_s;
    __syncthreads();
    if (!sup){
      if (tid == 0){
        kx1[kept]=ox1; ky1[kept]=oy1; kx2[kept]=ox2; ky2[kept]=oy2; kar[kept]=area; klv[kept]=lv;
        float* orow = out + (size_t)n*PRE*5 + (size_t)kept*5;
        orow[0]=b.x; orow[1]=b.y; orow[2]=b.z; orow[3]=b.w;
        orow[4]=sskey[(size_t)n*K_SEL + i];
      }
      ++kept;
    }
    if (tid == 0) flag_s = 0;
    __syncthreads();
    if (kept == PRE) break;
  }
}

extern "C" void kernel_launch(void* const* d_in, const int* in_sizes, int n_in,
                              void* d_out, int out_size, void* d_ws, size_t ws_size,
                              hipStream_t stream) {
  bool interleaved = (in_sizes[1] == 4*in_sizes[0]);
  const float* obj[5]; const float* dlt[5];
  for (int i = 0; i < 5; ++i){
    if (interleaved){ obj[i] = (const float*)d_in[2*i]; dlt[i] = (const float*)d_in[2*i+1]; }
    else            { obj[i] = (const float*)d_in[i];   dlt[i] = (const float*)d_in[5+i]; }
  }
  const float* anchors = (const float*)d_in[10];

  char* ws = (char*)d_ws;
  unsigned* hist            = (unsigned*)(ws);                     // 655360
  unsigned* cnt_gt          = (unsigned*)(ws + 655360);            // 160
  unsigned* cnt_eq          = (unsigned*)(ws + 655520);            // 160
  unsigned* thi             = (unsigned*)(ws + 655680);            // 160 -> counters end 655840
  unsigned long long* cand  = (unsigned long long*)(ws + 655840);  // 1310720 -> 1966560
  unsigned long long* keys  = (unsigned long long*)(ws + 1966560); // 320000 -> 2286560
  float4* lbox              = (float4*)(ws + 2286560);             // 640000 -> 2926560
  float4* lobox             = (float4*)(ws + 2926560);             // 640000 -> 3566560
  float* loarea             = (float*)(ws + 3566560);              // 160000 -> 3726560
  float* lskey              = (float*)(ws + 3726560);              // 160000 -> 3886560
  unsigned* rankinfo        = (unsigned*)(ws + 3886560);           // 160000 -> 4046560
  unsigned* lmat            = (unsigned*)(ws + 4046560);           // 5120000 -> 9166560
  float4* sbox              = (float4*)(ws + 9166560);             // fallback: 640000 -> 9806560
  float* sskey              = (float*)(ws + 9806560);              // 160000 -> 9966560
  int* slvl                 = (int*)(ws + 9966560);                // 160000 -> 10126560
  const size_t NEED = 10126560;

  hipMemsetAsync(ws, 0, 655840, stream);   // hist + counters

  dim3 gScan(8, 40);
  k_hist<<<gScan, 256, 0, stream>>>(obj[0],obj[1],obj[2],obj[3],obj[4], hist);
  k_scan<<<40, 256, 0, stream>>>(hist, thi);
  k_compact<<<gScan, 256, 0, stream>>>(obj[0],obj[1],obj[2],obj[3],obj[4],
                                       dlt[0],dlt[1],dlt[2],dlt[3],dlt[4],
                                       anchors, thi, cnt_gt, cnt_eq, cand, keys);
  k_tiesel<<<40, 256, 0, stream>>>(dlt[0],dlt[1],dlt[2],dlt[3],dlt[4], anchors,
                                   cnt_gt, cnt_eq, cand, keys);
  if (ws_size >= NEED){
    k_sortlvl<<<40, 256, 0, stream>>>(keys, dlt[0],dlt[1],dlt[2],dlt[3],dlt[4], anchors,
                                      lbox, lobox, loarea, lskey);
    k_rank<<<40, 256, 0, stream>>>(keys, rankinfo);
    k_ioumat_lvl<<<dim3(4, 40), 256, 0, stream>>>(lobox, loarea, lmat);
    hipMemsetAsync(d_out, 0, (size_t)out_size*sizeof(float), stream);
    k_scan_nms3<<<8, 64, 0, stream>>>(rankinfo, lmat, lbox, lskey, (float*)d_out);
  } else {
    k_sortimg<<<8, 256, 0, stream>>>(keys, dlt[0],dlt[1],dlt[2],dlt[3],dlt[4], anchors,
                                     sbox, sskey, slvl);
    k_nms<<<8, 256, 0, stream>>>(sbox, sskey, slvl, (float*)d_out);
  }
}

// Round 7
// 628.605 us; speedup vs baseline: 1.2873x; 1.0148x over previous
//
#include <hip/hip_runtime.h>
#include <cmath>

#define N_IMG   8
#define PRE     1000
#define K_SEL   5000
#define NBIN    4096
#define TIE_CAP 4096
#define IMG_F   1344.0f
#define S_NEGINF 0x007FFFFFu
#define TILES   79             // ceil(5000/64)

__constant__ int c_W[5]   = {336,168,84,42,21};
__constant__ int c_HW[5]  = {112896,28224,7056,1764,441};
__constant__ int c_OFF[5] = {0,338688,423360,444528,449820};

__device__ __forceinline__ unsigned f2s(float f){
  unsigned u = __float_as_uint(f);
  return (u & 0x80000000u) ? ~u : (u | 0x80000000u);
}
__device__ __forceinline__ float s2f(unsigned s){
  unsigned u = (s & 0x80000000u) ? (s & 0x7FFFFFFFu) : ~s;
  return __uint_as_float(u);
}
__device__ __forceinline__ const float* sel5(int l, const float* p0,const float* p1,const float* p2,const float* p3,const float* p4){
  switch(l){case 0:return p0;case 1:return p1;case 2:return p2;case 3:return p3;default:return p4;}
}

struct BoxV { float x1,y1,x2,y2; bool valid; };

// Bit-faithful torchvision BoxCoder.decode + clip + min-size validity.
__device__ BoxV decode_box(int lvl, int t, int n, const float* dl, const float* anchors){
  int HW = c_HW[lvl], W = c_W[lvl];
  int a = t % 3, pos = t / 3;          // t = (h*W+w)*3 + a
  int h = pos / W, w = pos - h*W;
  int g = c_OFF[lvl] + t;
  const float* an = anchors + (size_t)4*(size_t)g;
  float a0=an[0], a1=an[1], a2=an[2], a3=an[3];
  float aw = __fsub_rn(a2,a0), ah = __fsub_rn(a3,a1);
  float acx = __fadd_rn(a0, __fmul_rn(0.5f,aw));
  float acy = __fadd_rn(a1, __fmul_rn(0.5f,ah));
  const float* dp = dl + ((size_t)n*12 + (size_t)a*4)*(size_t)HW + (size_t)h*W + (size_t)w;
  float dx = dp[0], dy = dp[HW], dwv = dp[2*(size_t)HW], dhv = dp[3*(size_t)HW];
  const float CLAMP = (float)4.135166556742356;  // log(1000/16)
  dwv = fminf(dwv, CLAMP); dhv = fminf(dhv, CLAMP);
  float pcx = __fadd_rn(__fmul_rn(dx,aw), acx);
  float pcy = __fadd_rn(__fmul_rn(dy,ah), acy);
  float pw = __fmul_rn((float)::exp((double)dwv), aw);
  float ph = __fmul_rn((float)::exp((double)dhv), ah);
  float hx = __fmul_rn(0.5f,pw), hy = __fmul_rn(0.5f,ph);
  BoxV b;
  b.x1 = fminf(fmaxf(__fsub_rn(pcx,hx),0.0f),IMG_F);
  b.y1 = fminf(fmaxf(__fsub_rn(pcy,hy),0.0f),IMG_F);
  b.x2 = fminf(fmaxf(__fadd_rn(pcx,hx),0.0f),IMG_F);
  b.y2 = fminf(fmaxf(__fadd_rn(pcy,hy),0.0f),IMG_F);
  b.valid = (__fsub_rn(b.x2,b.x1) >= 1e-3f) && (__fsub_rn(b.y2,b.y1) >= 1e-3f);
  return b;
}

// key = (~s_eff)<<22 | lvl<<19 | t : ascending sort == (score desc, level asc, idx asc)
__device__ unsigned long long make_key(unsigned s, int lvl, int t, int n, const float* dl, const float* anchors){
  BoxV b = decode_box(lvl,t,n,dl,anchors);
  unsigned se = b.valid ? s : S_NEGINF;     // invalid -> skey = -inf
  return ((unsigned long long)(~se) << 22) | ((unsigned long long)(unsigned)lvl << 19) | (unsigned long long)(unsigned)t;
}

// ---------------- K1: per-(image,level) 12-bit score histogram ----------------
__global__ __launch_bounds__(256) void k_hist(const float* o0,const float* o1,const float* o2,const float* o3,const float* o4,
                                              unsigned* hist){
  int grp = blockIdx.y; int n = grp/5, lvl = grp - n*5;
  const float* ob = sel5(lvl,o0,o1,o2,o3,o4);
  int HW = c_HW[lvl], M = 3*HW;
  ob += (size_t)n*(size_t)M;
  __shared__ unsigned lh[NBIN];
  for (int b = threadIdx.x; b < NBIN; b += 256) lh[b] = 0;
  __syncthreads();
  int stride = gridDim.x*256;
  for (int i = blockIdx.x*256 + threadIdx.x; i < M; i += stride){
    unsigned s = f2s(ob[i]);
    atomicAdd(&lh[s >> 20], 1u);
  }
  __syncthreads();
  unsigned* gh = hist + (size_t)grp*NBIN;
  for (int b = threadIdx.x; b < NBIN; b += 256){ unsigned v = lh[b]; if (v) atomicAdd(&gh[b], v); }
}

// ---------------- K2: find bin containing the 1000th-largest score ----------------
__global__ __launch_bounds__(256) void k_scan(const unsigned* hist, unsigned* thi){
  int grp = blockIdx.x;
  const unsigned* gh = hist + (size_t)grp*NBIN;
  __shared__ unsigned part[256];
  unsigned ssum = 0;
  int base = threadIdx.x*16;
  for (int b = base; b < base+16; ++b) ssum += gh[b];
  part[threadIdx.x] = ssum;
  __syncthreads();
  if (threadIdx.x == 0){
    int k = PRE;
    int c = 255;
    while ((int)part[c] < k){ k -= (int)part[c]; --c; }
    int b = c*16 + 15;
    while ((int)gh[b] < k){ k -= (int)gh[b]; --b; }
    thi[grp] = (unsigned)b;
  }
}

// ---------------- K3: compact >bin elements (decode+key), collect ==bin candidates ----------------
__global__ __launch_bounds__(256) void k_compact(const float* o0,const float* o1,const float* o2,const float* o3,const float* o4,
                                                 const float* d0,const float* d1,const float* d2,const float* d3,const float* d4,
                                                 const float* anchors, const unsigned* thi,
                                                 unsigned* cnt_gt, unsigned* cnt_eq,
                                                 unsigned long long* cand, unsigned long long* keys){
  int grp = blockIdx.y; int n = grp/5, lvl = grp - n*5;
  const float* ob = sel5(lvl,o0,o1,o2,o3,o4);
  const float* dl = sel5(lvl,d0,d1,d2,d3,d4);
  int HW = c_HW[lvl], M = 3*HW;
  ob += (size_t)n*(size_t)M;
  unsigned T = thi[grp];
  unsigned long long* kout = keys + (size_t)n*K_SEL + (size_t)lvl*PRE;
  int stride = gridDim.x*256;
  for (int i = blockIdx.x*256 + threadIdx.x; i < M; i += stride){
    unsigned s = f2s(ob[i]);
    unsigned sh = s >> 20;
    if (sh > T){
      unsigned pos = atomicAdd(&cnt_gt[grp], 1u);
      int a = i / HW; int rem = i - a*HW; int t = rem*3 + a;
      kout[pos] = make_key(s, lvl, t, n, dl, anchors);
    } else if (sh == T){
      unsigned e = atomicAdd(&cnt_eq[grp], 1u);
      if (e < TIE_CAP){
        int a = i / HW; int rem = i - a*HW; int t = rem*3 + a;
        cand[(size_t)grp*TIE_CAP + e] = ((unsigned long long)(~s) << 19) | (unsigned long long)(unsigned)t;
      }
    }
  }
}

template<int SZ>
__device__ void bitonic(unsigned long long* sk){
  for (int k = 2; k <= SZ; k <<= 1){
    for (int j = k >> 1; j > 0; j >>= 1){
      for (int i = threadIdx.x; i < SZ; i += blockDim.x){
        int ix = i ^ j;
        if (ix > i){
          unsigned long long va = sk[i], vb = sk[ix];
          if ((va > vb) == ((i & k) == 0)){ sk[i] = vb; sk[ix] = va; }
        }
      }
      __syncthreads();
    }
  }
}

// runtime-sized bitonic (SZ uniform across block, power of 2)
__device__ void bitonic_rt(unsigned long long* sk, int SZ){
  for (int k = 2; k <= SZ; k <<= 1){
    for (int j = k >> 1; j > 0; j >>= 1){
      for (int i = threadIdx.x; i < SZ; i += blockDim.x){
        int ix = i ^ j;
        if (ix > i){
          unsigned long long va = sk[i], vb = sk[ix];
          if ((va > vb) == ((i & k) == 0)){ sk[i] = vb; sk[ix] = va; }
        }
      }
      __syncthreads();
    }
  }
}

// ---------------- K4: exact boundary selection within the threshold bin ----------------
__global__ __launch_bounds__(256) void k_tiesel(const float* d0,const float* d1,const float* d2,const float* d3,const float* d4,
                                                const float* anchors,
                                                const unsigned* cnt_gt, const unsigned* cnt_eq,
                                                const unsigned long long* cand, unsigned long long* keys){
  int grp = blockIdx.x; int n = grp/5, lvl = grp - n*5;
  __shared__ unsigned long long sk[TIE_CAP];
  int ne = min((int)cnt_eq[grp], TIE_CAP);
  int SZ = 64; while (SZ < ne) SZ <<= 1;    // runtime pow2 >= ne (uniform)
  for (int i = threadIdx.x; i < SZ; i += 256)
    sk[i] = (i < ne) ? cand[(size_t)grp*TIE_CAP + i] : ~0ULL;
  __syncthreads();
  bitonic_rt(sk, SZ);                // ascending: (score desc, idx asc)
  int cg = (int)cnt_gt[grp];
  int need = PRE - cg;
  const float* dl = sel5(lvl,d0,d1,d2,d3,d4);
  unsigned long long* kout = keys + (size_t)n*K_SEL + (size_t)lvl*PRE + cg;
  for (int j = threadIdx.x; j < need; j += 256){
    if (j < ne){
      unsigned long long ck = sk[j];
      unsigned t = (unsigned)(ck & 0x7FFFFu);
      unsigned s = ~((unsigned)(ck >> 19));
      kout[j] = make_key(s, lvl, (int)t, n, dl, anchors);
    } else {
      kout[j] = ((unsigned long long)(~S_NEGINF) << 22); // pathological overflow: harmless invalid
    }
  }
}

// ---------------- K5a: sort each (image,level) run; decode level-space arrays ----------------
__global__ __launch_bounds__(256) void k_sortlvl(unsigned long long* keys,
                                                 const float* d0,const float* d1,const float* d2,const float* d3,const float* d4,
                                                 const float* anchors,
                                                 float4* lbox, float4* lobox, float* loarea, float* lskey){
  int grp = blockIdx.x; int n = grp/5, lvl = grp - n*5;
  __shared__ unsigned long long sk[1024];
  unsigned long long* kp = keys + (size_t)n*K_SEL + (size_t)lvl*PRE;
  for (int i = threadIdx.x; i < 1024; i += 256)
    sk[i] = (i < PRE) ? kp[i] : ~0ULL;
  __syncthreads();
  bitonic<1024>(sk);
  const float* dl = sel5(lvl,d0,d1,d2,d3,d4);
  for (int i = threadIdx.x; i < PRE; i += 256){
    unsigned long long key = sk[i];
    kp[i] = key;                          // sorted run back to global (k_rank reads it)
    int t = (int)(key & 0x7FFFFu);
    unsigned se = ~((unsigned)(key >> 22));
    BoxV b = decode_box(lvl, t, n, dl, anchors);
    size_t o = (size_t)grp*PRE + i;
    lbox[o] = make_float4(b.x1,b.y1,b.x2,b.y2);
    lskey[o] = s2f(se);                   // -inf if invalid
    float off = (float)lvl * 1345.0f;     // (IMG+1) batched-NMS offset
    float ox1 = __fadd_rn(b.x1, off), oy1 = __fadd_rn(b.y1, off);
    float ox2 = __fadd_rn(b.x2, off), oy2 = __fadd_rn(b.y2, off);
    lobox[o] = make_float4(ox1,oy1,ox2,oy2);
    loarea[o] = __fmul_rn(__fsub_rn(ox2,ox1), __fsub_rn(oy2,oy1));
  }
}

// ---------------- K5b: global rank of each level element (keys globally unique) ----------------
// rankinfo[rank] = p | (lvl<<10) | (valid<<13)
__global__ __launch_bounds__(256) void k_rank(const unsigned long long* keys, unsigned* rankinfo){
  int grp = blockIdx.x; int n = grp/5, lvl = grp - n*5;
  __shared__ unsigned long long sl[K_SEL];
  for (int i = threadIdx.x; i < K_SEL; i += 256) sl[i] = keys[(size_t)n*K_SEL + i];
  __syncthreads();
  for (int j = threadIdx.x; j < PRE; j += 256){
    unsigned long long k = sl[lvl*PRE + j];
    int rank = j;
    #pragma unroll
    for (int m = 0; m < 5; ++m){
      if (m == lvl) continue;
      const unsigned long long* s = sl + m*PRE;
      int lo = 0, hi = PRE;
      while (lo < hi){ int mid = (lo+hi) >> 1; if (s[mid] < k) lo = mid+1; else hi = mid; }
      rank += lo;
    }
    unsigned se = ~((unsigned)(k >> 22));
    unsigned info = (unsigned)j | ((unsigned)lvl << 10) | ((se != S_NEGINF) ? (1u<<13) : 0u);
    rankinfo[(size_t)n*K_SEL + rank] = info;   // exact permutation of [0,5000)
  }
}

// ---------------- K6a: per-level suppression bit-matrix (block-diagonal; j>p) ----------------
__global__ __launch_bounds__(256) void k_ioumat_lvl(const float4* lobox, const float* loarea, unsigned* lmat){
  int grp = blockIdx.y;                  // n*5 + L
  int chunk = blockIdx.x;                // 4 chunks x 250 rows
  __shared__ float sx1[1024], sy1[1024], sx2[1024], sy2[1024], sar[1024];
  for (int i = threadIdx.x; i < 1024; i += 256){
    float4 bb = make_float4(0.f,0.f,0.f,0.f); float ar = 0.f;
    if (i < PRE){ bb = lobox[(size_t)grp*PRE + i]; ar = loarea[(size_t)grp*PRE + i]; }
    sx1[i]=bb.x; sy1[i]=bb.y; sx2[i]=bb.z; sy2[i]=bb.w; sar[i]=ar;
  }
  __syncthreads();
  int p0 = chunk*250;
  unsigned* mg = lmat + (size_t)grp*PRE*32;
  for (int task = threadIdx.x; task < 250*32; task += 256){
    int p = p0 + (task >> 5), w = task & 31;
    unsigned bits = 0u;
    if (w*32 + 31 > p){
      float bx1=sx1[p], by1=sy1[p], bx2=sx2[p], by2=sy2[p], ba=sar[p];
      #pragma unroll
      for (int jj = 0; jj < 32; ++jj){
        int js = (jj + w) & 31;          // per-lane rotation -> conflict-free LDS banks
        int j = (w<<5) + js;
        float ltx = fmaxf(bx1, sx1[j]), lty = fmaxf(by1, sy1[j]);
        float rbx = fminf(bx2, sx2[j]), rby = fminf(by2, sy2[j]);
        float ww_ = fmaxf(__fsub_rn(rbx,ltx), 0.0f);
        float hh_ = fmaxf(__fsub_rn(rby,lty), 0.0f);
        float inter = __fmul_rn(ww_,hh_);
        float uni = __fsub_rn(__fadd_rn(ba, sar[j]), inter);
        bool hit = (__fdiv_rn(inter,uni) > 0.7f) && (j > p);   // j>=1000 pad boxes give inter=0
        bits |= (hit ? 1u : 0u) << js;
      }
    }
    mg[(size_t)p*32 + w] = bits;
  }
}

// ---------------- K6b: tile-parallel greedy scan, one wave per image ----------------
// Tile rows staged in LDS (no VGPR arrays -> no spill). Per tile: 8x{bpermute,
// dwordx4 load, b128 LDS write} staging (prefetched one tile ahead), conflict-free
// LDS matrix build, 64-step scalar greedy core, lane-parallel output.
__global__ __launch_bounds__(64) void k_scan_nms4(const unsigned* rankinfo, const unsigned* lmat,
                                                  const float4* lbox, const float* lskey, float* out){
  __shared__ unsigned lrows[64][36];     // row stride 36 words: 16B-aligned, bank-rotated
  int n = blockIdx.x; int lane = threadIdx.x;
  int n5 = n*5;
  const unsigned* rin = rankinfo + (size_t)n*K_SEL;
  float* outn = out + (size_t)n*PRE*5;
  unsigned sup0=0u,sup1=0u,sup2=0u,sup3=0u,sup4=0u;
  int kept_total = 0;
  uint4 La,Lb,Lc,Ld,Le,Lf,Lg,Lh;         // staging regs: 8 x 16B = one tile's 64x128B rows
  float4 boxP; float scP = 0.f;
  unsigned infoC, infoN;
  int rsub = lane >> 3;                  // row-within-group
  int csub = (lane & 7) << 2;            // word offset of my 16B chunk

#define SLOAD(INFO) { \
    unsigned L_ = ((INFO)>>10)&7u; unsigned p_ = (INFO) & 1023u; \
    unsigned rowu_ = (((unsigned)n5 + L_)*PRE + p_) << 5; \
    unsigned rb_; \
    rb_ = __shfl(rowu_,  0 + rsub); La = *(const uint4*)(lmat + rb_ + csub); \
    rb_ = __shfl(rowu_,  8 + rsub); Lb = *(const uint4*)(lmat + rb_ + csub); \
    rb_ = __shfl(rowu_, 16 + rsub); Lc = *(const uint4*)(lmat + rb_ + csub); \
    rb_ = __shfl(rowu_, 24 + rsub); Ld = *(const uint4*)(lmat + rb_ + csub); \
    rb_ = __shfl(rowu_, 32 + rsub); Le = *(const uint4*)(lmat + rb_ + csub); \
    rb_ = __shfl(rowu_, 40 + rsub); Lf = *(const uint4*)(lmat + rb_ + csub); \
    rb_ = __shfl(rowu_, 48 + rsub); Lg = *(const uint4*)(lmat + rb_ + csub); \
    rb_ = __shfl(rowu_, 56 + rsub); Lh = *(const uint4*)(lmat + rb_ + csub); \
    size_t bi_ = (size_t)((unsigned)n5 + L_)*PRE + p_; \
    boxP = lbox[bi_]; scP = lskey[bi_]; }

#define SWRITE() { \
    *(uint4*)&lrows[ 0 + rsub][csub] = La; *(uint4*)&lrows[ 8 + rsub][csub] = Lb; \
    *(uint4*)&lrows[16 + rsub][csub] = Lc; *(uint4*)&lrows[24 + rsub][csub] = Ld; \
    *(uint4*)&lrows[32 + rsub][csub] = Le; *(uint4*)&lrows[40 + rsub][csub] = Lf; \
    *(uint4*)&lrows[48 + rsub][csub] = Lg; *(uint4*)&lrows[56 + rsub][csub] = Lh; }

#define TPROC(INFO, BOX, SC, baseexpr) { \
    int base_ = (baseexpr); \
    unsigned L_ = ((INFO)>>10)&7u; unsigned p_ = (INFO) & 1023u; \
    bool ok_ = ((((INFO)>>13)&1u) != 0u) && (base_ + lane < K_SEL); \
    int idxw_ = (int)(p_ >> 5); unsigned pb_ = p_ & 31u; \
    unsigned t0_=__shfl(sup0,idxw_), t1_=__shfl(sup1,idxw_), t2_=__shfl(sup2,idxw_), t3_=__shfl(sup3,idxw_), t4_=__shfl(sup4,idxw_); \
    unsigned sw_ = (L_==0u)?t0_:(L_==1u)?t1_:(L_==2u)?t2_:(L_==3u)?t3_:t4_; \
    bool pre_ = (!ok_) || (((sw_ >> pb_) & 1u) != 0u); \
    unsigned long long preM_ = __ballot(pre_); \
    unsigned cmlo_ = 0u, cmhi_ = 0u; \
    _Pragma("unroll") \
    for (int m_=0; m_<64; ++m_){ \
      unsigned infoM_ = __builtin_amdgcn_readlane((INFO), m_); \
      unsigned Lm_ = (infoM_>>10)&7u; \
      unsigned w_ = lrows[m_][idxw_]; \
      unsigned bit_ = ((w_ >> pb_) & 1u) & ((L_ == Lm_) ? 1u : 0u); \
      if (m_ < 32) cmlo_ |= bit_ << m_; else cmhi_ |= bit_ << (m_-32); \
    } \
    unsigned long long keptM_ = 0ull; \
    _Pragma("unroll") \
    for (int m_=0; m_<64; ++m_){ \
      unsigned long long cml_ = ((unsigned long long)__builtin_amdgcn_readlane(cmhi_, m_) << 32) \
                              |  (unsigned long long)__builtin_amdgcn_readlane(cmlo_, m_); \
      bool keep_ = (((preM_>>m_)&1ull) == 0ull) && ((cml_ & keptM_) == 0ull); \
      if (keep_) keptM_ |= (1ull<<m_); \
    } \
    unsigned myw_ = (unsigned)(lane & 31); \
    _Pragma("unroll") \
    for (int m_=0; m_<64; ++m_){ \
      if ((keptM_>>m_)&1ull){ \
        unsigned infoM_ = __builtin_amdgcn_readlane((INFO), m_); \
        unsigned Lm_ = (infoM_>>10)&7u; \
        unsigned rw_ = lrows[m_][myw_]; \
        switch(Lm_){ case 0u: sup0|=rw_; break; case 1u: sup1|=rw_; break; \
                     case 2u: sup2|=rw_; break; case 3u: sup3|=rw_; break; default: sup4|=rw_; } \
      } \
    } \
    int pos_ = kept_total + (int)__popcll(keptM_ & ((1ull<<lane)-1ull)); \
    if (((keptM_>>lane)&1ull) && pos_ < PRE){ \
      float* orow_ = outn + (size_t)pos_*5; \
      orow_[0]=(BOX).x; orow_[1]=(BOX).y; orow_[2]=(BOX).z; orow_[3]=(BOX).w; orow_[4]=(SC); \
    } \
    kept_total += (int)__popcll(keptM_); \
  }

  infoC = rin[lane];
  SLOAD(infoC);                          // tile 0 rows -> regs, box -> boxP
  SWRITE();                              // tile 0 rows -> LDS (waits its own loads once)
  float4 boxC = boxP; float scC = scP;
  infoN = rin[64 + lane];

  for (int t = 0; t < TILES; ++t){
    if (t+1 < TILES) SLOAD(infoN);       // issue next tile's loads (rows + box)
    asm volatile("s_waitcnt lgkmcnt(0)" ::: "memory");   // lrows writes visible
    TPROC(infoC, boxC, scC, t*64);
    if (kept_total >= PRE) break;
    if (t+1 < TILES){
      SWRITE();                          // waits next tile's loads (covered by TPROC)
      boxC = boxP; scC = scP;
      infoC = infoN;
      if (t+2 < TILES){
        int nx = (t+2)*64 + lane; if (nx > K_SEL-1) nx = K_SEL-1;
        infoN = rin[nx];
      }
    }
  }
#undef SLOAD
#undef SWRITE
#undef TPROC
}

// ---------------- fallback path (ws too small): round-3 kernels ----------------
__global__ __launch_bounds__(256) void k_sortimg(const unsigned long long* keys,
                                                 const float* d0,const float* d1,const float* d2,const float* d3,const float* d4,
                                                 const float* anchors,
                                                 float4* sbox, float* sskey, int* slvl){
  int n = blockIdx.x;
  __shared__ unsigned long long sk[8192];
  for (int i = threadIdx.x; i < 8192; i += 256)
    sk[i] = (i < K_SEL) ? keys[(size_t)n*K_SEL + i] : ~0ULL;
  __syncthreads();
  bitonic<8192>(sk);
  for (int r = threadIdx.x; r < K_SEL; r += 256){
    unsigned long long key = sk[r];
    int t = (int)(key & 0x7FFFFu);
    int lvl = (int)((key >> 19) & 7u);
    unsigned se = ~((unsigned)(key >> 22));
    const float* dl = sel5(lvl,d0,d1,d2,d3,d4);
    BoxV b = decode_box(lvl, t, n, dl, anchors);
    sbox[(size_t)n*K_SEL + r] = make_float4(b.x1,b.y1,b.x2,b.y2);
    sskey[(size_t)n*K_SEL + r] = s2f(se);
    slvl[(size_t)n*K_SEL + r] = lvl;
  }
}

__global__ __launch_bounds__(256) void k_nms(const float4* sbox, const float* sskey, const int* slvl, float* out){
  int n = blockIdx.x, tid = threadIdx.x;
  __shared__ float kx1[PRE], ky1[PRE], kx2[PRE], ky2[PRE], kar[PRE];
  __shared__ int klv[PRE];
  __shared__ int nv_s, flag_s;
  for (int i = tid; i < PRE*5; i += 256) out[(size_t)n*PRE*5 + i] = 0.0f;
  if (tid == 0){ nv_s = 0; flag_s = 0; }
  __syncthreads();
  int c = 0;
  for (int i = tid; i < K_SEL; i += 256)
    if (sskey[(size_t)n*K_SEL + i] != -INFINITY) ++c;
  atomicAdd(&nv_s, c);
  __syncthreads();
  int nvalid = nv_s;
  int kept = 0;
  for (int i = 0; i < nvalid; ++i){
    float4 b = sbox[(size_t)n*K_SEL + i];
    int lv = slvl[(size_t)n*K_SEL + i];
    float off = (float)lv * 1345.0f;
    float ox1 = __fadd_rn(b.x, off), oy1 = __fadd_rn(b.y, off);
    float ox2 = __fadd_rn(b.z, off), oy2 = __fadd_rn(b.w, off);
    float area = __fmul_rn(__fsub_rn(ox2,ox1), __fsub_rn(oy2,oy1));
    bool hit = false;
    for (int j = tid; j < kept; j += 256){
      if (klv[j] == lv){
        float ltx = fmaxf(kx1[j], ox1), lty = fmaxf(ky1[j], oy1);
        float rbx = fminf(kx2[j], ox2), rby = fminf(ky2[j], oy2);
        float w = fmaxf(__fsub_rn(rbx,ltx), 0.0f);
        float h = fmaxf(__fsub_rn(rby,lty), 0.0f);
        float inter = __fmul_rn(w,h);
        float uni = __fsub_rn(__fadd_rn(kar[j], area), inter);
        if (__fdiv_rn(inter,uni) > 0.7f) hit = true;
      }
    }
    if (hit) flag_s = 1;
    __syncthreads();
    int sup = flag_s;
    __syncthreads();
    if (!sup){
      if (tid == 0){
        kx1[kept]=ox1; ky1[kept]=oy1; kx2[kept]=ox2; ky2[kept]=oy2; kar[kept]=area; klv[kept]=lv;
        float* orow = out + (size_t)n*PRE*5 + (size_t)kept*5;
        orow[0]=b.x; orow[1]=b.y; orow[2]=b.z; orow[3]=b.w;
        orow[4]=sskey[(size_t)n*K_SEL + i];
      }
      ++kept;
    }
    if (tid == 0) flag_s = 0;
    __syncthreads();
    if (kept == PRE) break;
  }
}

extern "C" void kernel_launch(void* const* d_in, const int* in_sizes, int n_in,
                              void* d_out, int out_size, void* d_ws, size_t ws_size,
                              hipStream_t stream) {
  bool interleaved = (in_sizes[1] == 4*in_sizes[0]);
  const float* obj[5]; const float* dlt[5];
  for (int i = 0; i < 5; ++i){
    if (interleaved){ obj[i] = (const float*)d_in[2*i]; dlt[i] = (const float*)d_in[2*i+1]; }
    else            { obj[i] = (const float*)d_in[i];   dlt[i] = (const float*)d_in[5+i]; }
  }
  const float* anchors = (const float*)d_in[10];

  char* ws = (char*)d_ws;
  unsigned* hist            = (unsigned*)(ws);                     // 655360
  unsigned* cnt_gt          = (unsigned*)(ws + 655360);            // 160
  unsigned* cnt_eq          = (unsigned*)(ws + 655520);            // 160
  unsigned* thi             = (unsigned*)(ws + 655680);            // 160 -> counters end 655840
  unsigned long long* cand  = (unsigned long long*)(ws + 655840);  // 1310720 -> 1966560
  unsigned long long* keys  = (unsigned long long*)(ws + 1966560); // 320000 -> 2286560
  float4* lbox              = (float4*)(ws + 2286560);             // 640000 -> 2926560
  float4* lobox             = (float4*)(ws + 2926560);             // 640000 -> 3566560
  float* loarea             = (float*)(ws + 3566560);              // 160000 -> 3726560
  float* lskey              = (float*)(ws + 3726560);              // 160000 -> 3886560
  unsigned* rankinfo        = (unsigned*)(ws + 3886560);           // 160000 -> 4046560
  unsigned* lmat            = (unsigned*)(ws + 4046560);           // 5120000 -> 9166560
  float4* sbox              = (float4*)(ws + 9166560);             // fallback: 640000 -> 9806560
  float* sskey              = (float*)(ws + 9806560);              // 160000 -> 9966560
  int* slvl                 = (int*)(ws + 9966560);                // 160000 -> 10126560
  const size_t NEED = 10126560;

  hipMemsetAsync(ws, 0, 655840, stream);   // hist + counters

  dim3 gScan(8, 40);
  k_hist<<<gScan, 256, 0, stream>>>(obj[0],obj[1],obj[2],obj[3],obj[4], hist);
  k_scan<<<40, 256, 0, stream>>>(hist, thi);
  k_compact<<<gScan, 256, 0, stream>>>(obj[0],obj[1],obj[2],obj[3],obj[4],
                                       dlt[0],dlt[1],dlt[2],dlt[3],dlt[4],
                                       anchors, thi, cnt_gt, cnt_eq, cand, keys);
  k_tiesel<<<40, 256, 0, stream>>>(dlt[0],dlt[1],dlt[2],dlt[3],dlt[4], anchors,
                                   cnt_gt, cnt_eq, cand, keys);
  if (ws_size >= NEED){
    k_sortlvl<<<40, 256, 0, stream>>>(keys, dlt[0],dlt[1],dlt[2],dlt[3],dlt[4], anchors,
                                      lbox, lobox, loarea, lskey);
    k_rank<<<40, 256, 0, stream>>>(keys, rankinfo);
    k_ioumat_lvl<<<dim3(4, 40), 256, 0, stream>>>(lobox, loarea, lmat);
    hipMemsetAsync(d_out, 0, (size_t)out_size*sizeof(float), stream);
    k_scan_nms4<<<8, 64, 0, stream>>>(rankinfo, lmat, lbox, lskey, (float*)d_out);
  } else {
    k_sortimg<<<8, 256, 0, stream>>>(keys, dlt[0],dlt[1],dlt[2],dlt[3],dlt[4], anchors,
                                     sbox, sskey, slvl);
    k_nms<<<8, 256, 0, stream>>>(sbox, sskey, slvl, (float*)d_out);
  }
}